// Round 1
// baseline (377.572 us; speedup 1.0000x reference)
//
#include <hip/hip_runtime.h>

// Problem constants (from reference)
#define B_  16
#define T_  2048
#define IN_ 512
#define H_  512
#define M_  (B_ * T_)

// GEMM tiling — R5 structure, the measured local optimum (212us, VGPR 116).
// History: R6 (256,4) bound -> acc spill -> 3048us. R7 2-reg-set ping-pong
// -> VGPR 192 -> 298us. R8 persistent fusion -> occupancy coupling -> 529us.
// R9 1-barrier ping-pong -> mid-compute vmcnt drain -> 230us. KEEP THIS.
#define BM 128
#define BN 128
#define BK 16
#define LDT (BM + 4)

static __device__ __forceinline__ float4 ld4(const float* p) {
    return *reinterpret_cast<const float4*>(p);
}

// ---------------------------------------------------------------------------
// Kernel 1: h[m][n] = sum_k x[m][k]*W[n][k] + b[n], fp32 VALU.
// k accumulated strictly in order 0..511 with fmaf -> bit-matches np ref
// (absmax 0.0 across R2-R9). DO NOT reorder the k loop.
// Single LDS buffer + register prefetch of next k-tile (R5 body, verbatim).
// BYTE-IDENTICAL to the 370us round — do not touch this kernel.
// ---------------------------------------------------------------------------
__global__ __launch_bounds__(256)
void gemm_xwT(const float* __restrict__ X, const float* __restrict__ W,
              const float* __restrict__ bias, float* __restrict__ Hout) {
    __shared__ float As[BK][LDT];
    __shared__ float Bs[BK][LDT];

    const int tid = threadIdx.x;
    const int m0  = blockIdx.x * BM;   // 256 m-tiles
    const int n0  = blockIdx.y * BN;   // 4 n-tiles

    const int tx = tid & 15;           // col group
    const int ty = tid >> 4;           // row group

    const int row = tid >> 2;          // 0..63
    const int kph = (tid & 3) * 4;     // 0,4,8,12

    const float* pa0 = X + (size_t)(m0 + row) * IN_ + kph;
    const float* pa1 = pa0 + (size_t)64 * IN_;
    const float* pb0 = W + (size_t)(n0 + row) * IN_ + kph;
    const float* pb1 = pb0 + (size_t)64 * IN_;

    float4 ra0 = ld4(pa0), ra1 = ld4(pa1), rb0 = ld4(pb0), rb1 = ld4(pb1);

    float acc[8][8];
#pragma unroll
    for (int i = 0; i < 8; ++i)
#pragma unroll
        for (int j = 0; j < 8; ++j) acc[i][j] = 0.0f;

    for (int k0 = 0; k0 < IN_; k0 += BK) {
        As[kph + 0][row]      = ra0.x;  As[kph + 1][row]      = ra0.y;
        As[kph + 2][row]      = ra0.z;  As[kph + 3][row]      = ra0.w;
        As[kph + 0][row + 64] = ra1.x;  As[kph + 1][row + 64] = ra1.y;
        As[kph + 2][row + 64] = ra1.z;  As[kph + 3][row + 64] = ra1.w;
        Bs[kph + 0][row]      = rb0.x;  Bs[kph + 1][row]      = rb0.y;
        Bs[kph + 2][row]      = rb0.z;  Bs[kph + 3][row]      = rb0.w;
        Bs[kph + 0][row + 64] = rb1.x;  Bs[kph + 1][row + 64] = rb1.y;
        Bs[kph + 2][row + 64] = rb1.z;  Bs[kph + 3][row + 64] = rb1.w;
        __syncthreads();

        // prefetch next k-tile into registers; drains during the 16-k compute
        if (k0 + BK < IN_) {
            ra0 = ld4(pa0 + k0 + BK);  ra1 = ld4(pa1 + k0 + BK);
            rb0 = ld4(pb0 + k0 + BK);  rb1 = ld4(pb1 + k0 + BK);
        }

#pragma unroll
        for (int k = 0; k < BK; ++k) {
            float4 av0 = ld4(&As[k][ty * 4]);
            float4 av1 = ld4(&As[k][ty * 4 + 64]);
            float4 bv0 = ld4(&Bs[k][tx * 4]);
            float4 bv1 = ld4(&Bs[k][tx * 4 + 64]);
            const float am[8] = {av0.x, av0.y, av0.z, av0.w,
                                 av1.x, av1.y, av1.z, av1.w};
            const float bn8[8] = {bv0.x, bv0.y, bv0.z, bv0.w,
                                  bv1.x, bv1.y, bv1.z, bv1.w};
#pragma unroll
            for (int i = 0; i < 8; ++i)
#pragma unroll
                for (int j = 0; j < 8; ++j)
                    acc[i][j] = fmaf(am[i], bn8[j], acc[i][j]);
        }
        __syncthreads();
    }

    // epilogue: + bias (bias is zeros -> exact), coalesced float4 stores
    float4 bb0 = ld4(&bias[n0 + tx * 4]);
    float4 bb1 = ld4(&bias[n0 + tx * 4 + 64]);
#pragma unroll
    for (int i = 0; i < 8; ++i) {
        const int r = m0 + ((i < 4) ? (ty * 4 + i) : (64 + ty * 4 + (i - 4)));
        float4 o0, o1;
        o0.x = acc[i][0] + bb0.x;  o0.y = acc[i][1] + bb0.y;
        o0.z = acc[i][2] + bb0.z;  o0.w = acc[i][3] + bb0.w;
        o1.x = acc[i][4] + bb1.x;  o1.y = acc[i][5] + bb1.y;
        o1.z = acc[i][6] + bb1.z;  o1.w = acc[i][7] + bb1.w;
        *reinterpret_cast<float4*>(&Hout[(size_t)r * H_ + n0 + tx * 4])      = o0;
        *reinterpret_cast<float4*>(&Hout[(size_t)r * H_ + n0 + tx * 4 + 64]) = o1;
    }
}

// ---------------------------------------------------------------------------
// Kernel 2: GIF neuron scan. One thread per (b,h) chain; T=2048 steps.
// Wall = 2048 x loop-carried-dependence latency (~198 cy/step measured at the
// 10-op chain). R10 change: drop the Newton-Raphson refinement entirely and
// Markstein-correct directly off the raw v_rcp seed. Error analysis:
//   r0 within 1 ulp of 1/theta  ->  q0 = v*r0 has rel err eps <= ~1.8e-7
//   er = fma(-theta,q0,v) is the exact residual (single rounding of a value
//        that is itself only ~eps*v in magnitude)
//   q  = fma(er,r0,q0) cancels eps to O(eps^2) ~ 2e-14 rel, one final round.
// So q == RN(v/theta) except when v/theta is within ~2e-14 rel of a rounding
// boundary (~2.3e-7/op) AND that boundary is an integer 1..16 (~1e-6 of
// boundaries) -> ~1e-13/op * 16.8M divs ~ 2e-6 chance of a single floor flip.
// This shortens the loop-carried cycle from 10 dependent ops to 8:
//   s -> theta(2) -> rcp -> q0 -> er -> q -> floor -> med3 -> s
// theta in [1,17) always (convex update toward s+1>=1), so rcp is edge-free;
// theta=1.0 gives exact r0=1.0. v/theta update statements byte-identical to
// the validated round. DO NOT touch the v/theta arithmetic statements.
// ---------------------------------------------------------------------------
#define SPF 32

__device__ __forceinline__
void scan_steps(const float* __restrict__ buf, float* __restrict__ sp,
                int tb, float& v, float& theta) {
    const float DECAY_F = 0.9048374180359595f;  // exp(-1/10)
    const float ALPHA_F = 0.01f;
#pragma unroll
    for (int j = 0; j < SPF; ++j) {
        float cur = buf[j];
        v = v * DECAY_F + cur;
        float cl = 32.0f * theta;                  // L * theta * 2
        v = __builtin_amdgcn_fmed3f(v, -cl, cl);   // == fminf(fmaxf(v,-cl),cl)

        // ---- v/theta: raw rcp seed + Markstein correction (R10) ----
        float r0 = __builtin_amdgcn_rcpf(theta);   // ~1 ulp seed
        float q0 = v * r0;
        float er = fmaf(-theta, q0, v);            // exact residual
        float q  = fmaf(er, r0, q0);               // RN quotient to O(ulp^2)
        // ------------------------------------------------------------

        float s = floorf(q);
        s = __builtin_amdgcn_fmed3f(s, 0.0f, 16.0f); // == fminf(fmaxf(s,0),16)
        v = v - s * theta;
        theta = theta + ALPHA_F * s - ALPHA_F * (theta - 1.0f);
        sp[(size_t)(tb + j) * H_] = s;
    }
}

__global__ __launch_bounds__(64)
void gif_scan(const float* __restrict__ Hbuf, float* __restrict__ spikes,
              float* __restrict__ vout, float* __restrict__ thout) {
    const int gid = blockIdx.x * 64 + threadIdx.x;    // 0..8191
    const int b = gid >> 9;
    const int h = gid & 511;

    const float* ip = Hbuf   + (size_t)b * T_ * H_ + h;
    float*       sp = spikes + (size_t)b * T_ * H_ + h;

    float bufA[SPF], bufB[SPF];
#pragma unroll
    for (int j = 0; j < SPF; ++j) bufA[j] = ip[(size_t)j * H_];

    float v = 0.0f, theta = 1.0f;
    for (int t0 = 0; t0 < T_; t0 += 2 * SPF) {        // 32 iters, no tail
#pragma unroll
        for (int j = 0; j < SPF; ++j) bufB[j] = ip[(size_t)(t0 + SPF + j) * H_];
        asm volatile("" ::: "memory");
        scan_steps(bufA, sp, t0, v, theta);

        if (t0 + 2 * SPF < T_) {
#pragma unroll
            for (int j = 0; j < SPF; ++j)
                bufA[j] = ip[(size_t)(t0 + 2 * SPF + j) * H_];
        }
        asm volatile("" ::: "memory");
        scan_steps(bufB, sp, t0 + SPF, v, theta);
    }
    vout[gid]  = v;
    thout[gid] = theta;
}

// ---------------------------------------------------------------------------
extern "C" void kernel_launch(void* const* d_in, const int* in_sizes, int n_in,
                              void* d_out, int out_size, void* d_ws, size_t ws_size,
                              hipStream_t stream) {
    const float* x    = (const float*)d_in[0];   // [16, 2048, 512]
    const float* W    = (const float*)d_in[1];   // [512, 512]
    const float* bias = (const float*)d_in[2];   // [512]

    float* out    = (float*)d_out;
    float* spikes = out;
    float* v_f    = out + (size_t)M_ * H_;
    float* th_f   = v_f + (size_t)B_ * H_;

    float* hbuf   = (float*)d_ws;                // 64 MiB scratch for h

    dim3 grid(M_ / BM, H_ / BN);                 // 256 x 4
    gemm_xwT<<<grid, 256, 0, stream>>>(x, W, bias, hbuf);
    gif_scan<<<(B_ * H_) / 64, 64, 0, stream>>>(hbuf, spikes, v_f, th_f);
}

// Round 2
// 368.666 us; speedup vs baseline: 1.0242x; 1.0242x over previous
//
#include <hip/hip_runtime.h>

// Problem constants (from reference)
#define B_  16
#define T_  2048
#define IN_ 512
#define H_  512
#define M_  (B_ * T_)

// GEMM tiling — R5 structure, the measured local optimum (212us, VGPR 116).
// History: R6 (256,4) bound -> acc spill -> 3048us. R7 2-reg-set ping-pong
// -> VGPR 192 -> 298us. R8 persistent fusion -> occupancy coupling -> 529us.
// R9 1-barrier ping-pong -> mid-compute vmcnt drain -> 230us. KEEP THIS.
#define BM 128
#define BN 128
#define BK 16
#define LDT (BM + 4)

static __device__ __forceinline__ float4 ld4(const float* p) {
    return *reinterpret_cast<const float4*>(p);
}

// ---------------------------------------------------------------------------
// Kernel 1: h[m][n] = sum_k x[m][k]*W[n][k] + b[n], fp32 VALU.
// k accumulated strictly in order 0..511 with fmaf -> bit-matches np ref
// (absmax 0.0 across R2-R10). DO NOT reorder the k loop.
// Single LDS buffer + register prefetch of next k-tile (R5 body, verbatim).
// BYTE-IDENTICAL since the 370us round — do not touch this kernel.
// ---------------------------------------------------------------------------
__global__ __launch_bounds__(256)
void gemm_xwT(const float* __restrict__ X, const float* __restrict__ W,
              const float* __restrict__ bias, float* __restrict__ Hout) {
    __shared__ float As[BK][LDT];
    __shared__ float Bs[BK][LDT];

    const int tid = threadIdx.x;
    const int m0  = blockIdx.x * BM;   // 256 m-tiles
    const int n0  = blockIdx.y * BN;   // 4 n-tiles

    const int tx = tid & 15;           // col group
    const int ty = tid >> 4;           // row group

    const int row = tid >> 2;          // 0..63
    const int kph = (tid & 3) * 4;     // 0,4,8,12

    const float* pa0 = X + (size_t)(m0 + row) * IN_ + kph;
    const float* pa1 = pa0 + (size_t)64 * IN_;
    const float* pb0 = W + (size_t)(n0 + row) * IN_ + kph;
    const float* pb1 = pb0 + (size_t)64 * IN_;

    float4 ra0 = ld4(pa0), ra1 = ld4(pa1), rb0 = ld4(pb0), rb1 = ld4(pb1);

    float acc[8][8];
#pragma unroll
    for (int i = 0; i < 8; ++i)
#pragma unroll
        for (int j = 0; j < 8; ++j) acc[i][j] = 0.0f;

    for (int k0 = 0; k0 < IN_; k0 += BK) {
        As[kph + 0][row]      = ra0.x;  As[kph + 1][row]      = ra0.y;
        As[kph + 2][row]      = ra0.z;  As[kph + 3][row]      = ra0.w;
        As[kph + 0][row + 64] = ra1.x;  As[kph + 1][row + 64] = ra1.y;
        As[kph + 2][row + 64] = ra1.z;  As[kph + 3][row + 64] = ra1.w;
        Bs[kph + 0][row]      = rb0.x;  Bs[kph + 1][row]      = rb0.y;
        Bs[kph + 2][row]      = rb0.z;  Bs[kph + 3][row]      = rb0.w;
        Bs[kph + 0][row + 64] = rb1.x;  Bs[kph + 1][row + 64] = rb1.y;
        Bs[kph + 2][row + 64] = rb1.z;  Bs[kph + 3][row + 64] = rb1.w;
        __syncthreads();

        // prefetch next k-tile into registers; drains during the 16-k compute
        if (k0 + BK < IN_) {
            ra0 = ld4(pa0 + k0 + BK);  ra1 = ld4(pa1 + k0 + BK);
            rb0 = ld4(pb0 + k0 + BK);  rb1 = ld4(pb1 + k0 + BK);
        }

#pragma unroll
        for (int k = 0; k < BK; ++k) {
            float4 av0 = ld4(&As[k][ty * 4]);
            float4 av1 = ld4(&As[k][ty * 4 + 64]);
            float4 bv0 = ld4(&Bs[k][tx * 4]);
            float4 bv1 = ld4(&Bs[k][tx * 4 + 64]);
            const float am[8] = {av0.x, av0.y, av0.z, av0.w,
                                 av1.x, av1.y, av1.z, av1.w};
            const float bn8[8] = {bv0.x, bv0.y, bv0.z, bv0.w,
                                  bv1.x, bv1.y, bv1.z, bv1.w};
#pragma unroll
            for (int i = 0; i < 8; ++i)
#pragma unroll
                for (int j = 0; j < 8; ++j)
                    acc[i][j] = fmaf(am[i], bn8[j], acc[i][j]);
        }
        __syncthreads();
    }

    // epilogue: + bias (bias is zeros -> exact), coalesced float4 stores
    float4 bb0 = ld4(&bias[n0 + tx * 4]);
    float4 bb1 = ld4(&bias[n0 + tx * 4 + 64]);
#pragma unroll
    for (int i = 0; i < 8; ++i) {
        const int r = m0 + ((i < 4) ? (ty * 4 + i) : (64 + ty * 4 + (i - 4)));
        float4 o0, o1;
        o0.x = acc[i][0] + bb0.x;  o0.y = acc[i][1] + bb0.y;
        o0.z = acc[i][2] + bb0.z;  o0.w = acc[i][3] + bb0.w;
        o1.x = acc[i][4] + bb1.x;  o1.y = acc[i][5] + bb1.y;
        o1.z = acc[i][6] + bb1.z;  o1.w = acc[i][7] + bb1.w;
        *reinterpret_cast<float4*>(&Hout[(size_t)r * H_ + n0 + tx * 4])      = o0;
        *reinterpret_cast<float4*>(&Hout[(size_t)r * H_ + n0 + tx * 4 + 64]) = o1;
    }
}

// ---------------------------------------------------------------------------
// Kernel 2: GIF neuron scan. One thread per (b,h) chain; T=2048 steps.
// R11 POST-MORTEM of R10: shortening the ALU chain (10->8 ops) changed
// NOTHING (scan ~167us both rounds) -> the scan is NOT ALU-chain-bound.
// Revised theory: per-step global stores create a store-data REGISTER REUSE
// hazard. A VMEM store reads its data VGPR after issue; with `s` living in a
// tiny register rotation, every step must s_waitcnt a recent store before
// overwriting s. With 1 wave/SIMD there is zero TLP to hide that wait
// (~150cy/step of the measured 196cy/step).
// R11 change: split each 32-step batch into (a) a PURE-ALU compute phase that
// writes s into a 32-element register array (32 distinct store-data regs ->
// no reuse hazard inside a batch), then (b) a bulk store phase. Register
// reuse now happens 64 steps after the stores were issued -> drained.
// Arithmetic statements byte-identical to R10 (absmax 0.0). DO NOT touch.
// ---------------------------------------------------------------------------
#define SPF 32

__device__ __forceinline__
void scan_compute(const float* __restrict__ buf, float* __restrict__ sarr,
                  float& v, float& theta) {
    const float DECAY_F = 0.9048374180359595f;  // exp(-1/10)
    const float ALPHA_F = 0.01f;
#pragma unroll
    for (int j = 0; j < SPF; ++j) {
        float cur = buf[j];
        v = v * DECAY_F + cur;
        float cl = 32.0f * theta;                  // L * theta * 2
        v = __builtin_amdgcn_fmed3f(v, -cl, cl);   // == fminf(fmaxf(v,-cl),cl)

        // ---- v/theta: raw rcp seed + Markstein correction (validated) ----
        float r0 = __builtin_amdgcn_rcpf(theta);   // ~1 ulp seed
        float q0 = v * r0;
        float er = fmaf(-theta, q0, v);            // exact residual
        float q  = fmaf(er, r0, q0);               // RN quotient to O(ulp^2)
        // ------------------------------------------------------------------

        float s = floorf(q);
        s = __builtin_amdgcn_fmed3f(s, 0.0f, 16.0f); // == fminf(fmaxf(s,0),16)
        v = v - s * theta;
        theta = theta + ALPHA_F * s - ALPHA_F * (theta - 1.0f);
        sarr[j] = s;                               // register array, no store
    }
}

__device__ __forceinline__
void store_batch(float* __restrict__ sp, int tb, const float* __restrict__ sarr) {
#pragma unroll
    for (int j = 0; j < SPF; ++j)
        sp[(size_t)(tb + j) * H_] = sarr[j];
}

__global__ __launch_bounds__(64, 1)
void gif_scan(const float* __restrict__ Hbuf, float* __restrict__ spikes,
              float* __restrict__ vout, float* __restrict__ thout) {
    const int gid = blockIdx.x * 64 + threadIdx.x;    // 0..8191
    const int b = gid >> 9;
    const int h = gid & 511;

    const float* ip = Hbuf   + (size_t)b * T_ * H_ + h;
    float*       sp = spikes + (size_t)b * T_ * H_ + h;

    float bufA[SPF], bufB[SPF], sA[SPF], sB[SPF];
#pragma unroll
    for (int j = 0; j < SPF; ++j) bufA[j] = ip[(size_t)j * H_];

    float v = 0.0f, theta = 1.0f;
    for (int t0 = 0; t0 < T_; t0 += 2 * SPF) {        // 32 iters, no tail
        // prefetch next half-batch
#pragma unroll
        for (int j = 0; j < SPF; ++j) bufB[j] = ip[(size_t)(t0 + SPF + j) * H_];
        asm volatile("" ::: "memory");

        scan_compute(bufA, sA, v, theta);             // pure ALU
        store_batch(sp, t0, sA);                      // 32 bulk stores

        if (t0 + 2 * SPF < T_) {
#pragma unroll
            for (int j = 0; j < SPF; ++j)
                bufA[j] = ip[(size_t)(t0 + 2 * SPF + j) * H_];
        }
        asm volatile("" ::: "memory");

        scan_compute(bufB, sB, v, theta);             // pure ALU
        store_batch(sp, t0 + SPF, sB);                // 32 bulk stores
    }
    vout[gid]  = v;
    thout[gid] = theta;
}

// ---------------------------------------------------------------------------
extern "C" void kernel_launch(void* const* d_in, const int* in_sizes, int n_in,
                              void* d_out, int out_size, void* d_ws, size_t ws_size,
                              hipStream_t stream) {
    const float* x    = (const float*)d_in[0];   // [16, 2048, 512]
    const float* W    = (const float*)d_in[1];   // [512, 512]
    const float* bias = (const float*)d_in[2];   // [512]

    float* out    = (float*)d_out;
    float* spikes = out;
    float* v_f    = out + (size_t)M_ * H_;
    float* th_f   = v_f + (size_t)B_ * H_;

    float* hbuf   = (float*)d_ws;                // 64 MiB scratch for h

    dim3 grid(M_ / BM, H_ / BN);                 // 256 x 4
    gemm_xwT<<<grid, 256, 0, stream>>>(x, W, bias, hbuf);
    gif_scan<<<(B_ * H_) / 64, 64, 0, stream>>>(hbuf, spikes, v_f, th_f);
}